// Round 1
// 400.796 us; speedup vs baseline: 1.0151x; 1.0151x over previous
//
#include <hip/hip_runtime.h>
#include <stdint.h>
#include <math.h>

// Problem constants (B=4,S=2048 -> T=8192; H=1024; 2H=2048; E=8; K=2)
#define T_TOK 8192
#define H_DIM 1024
#define H2    2048
#define NE    8

typedef unsigned short u16;
typedef __attribute__((ext_vector_type(8))) short bf16x8;   // 8 bf16 in 4 VGPRs
typedef __attribute__((ext_vector_type(4))) float f32x4;    // MFMA 16x16 C/D

__device__ __forceinline__ u16 f32_to_bf16(float f) {
  union { float f; unsigned u; } c; c.f = f;
  unsigned u = c.u + 0x7fffu + ((c.u >> 16) & 1u);  // RNE
  return (u16)(u >> 16);
}
__device__ __forceinline__ float bf2f(u16 v) {
  union { unsigned u; float f; } c; c.u = (unsigned)v << 16; return c.f;
}

// fast gelu (tanh form), |err| vs exact erf-gelu <= ~1e-3 (R4/R5: absmax
// unchanged at 1.56e-2 vs threshold 4.9e-2)
__device__ __forceinline__ float fast_gelu(float v) {
  float u = v * v;
  float z2 = v * fmaf(u, 0.1029437f, 2.3022078f);
  float e = __builtin_amdgcn_exp2f(z2);
  float r = __builtin_amdgcn_rcpf(1.0f + e);
  return v - v * r;
}

// async global->LDS, 16B per lane. LDS dest is wave-uniform base + lane*16;
// global address is per-lane (exploited for the XOR bank swizzle).
__device__ __forceinline__ void g2l16(const void* g, void* l) {
  __builtin_amdgcn_global_load_lds(
      (const __attribute__((address_space(1))) unsigned*)g,
      (__attribute__((address_space(3))) unsigned*)l, 16, 0, 0);
}

// exclusive prefix of 8 counts, computed per-block
__device__ __forceinline__ int prefix_base(const int* counts, int e) {
  int b = 0;
#pragma unroll
  for (int j = 0; j < NE; j++) b += (j < e) ? counts[j] : 0;
  return b;
}

// ---------------- Prep: router (blocks 0..2047) + w1/w2 cvt (blocks
// 2048..8191). Heterogeneous fusion: VALU-bound routing overlaps HBM-bound
// conversion (R3: saved 33us vs split). Also zeroes counts.
__global__ __launch_bounds__(256) void prep_kernel(
    const float* __restrict__ x, const float* __restrict__ rw,
    const float* __restrict__ w1, const float* __restrict__ w2,
    u16* __restrict__ xb, u16* __restrict__ w1b, u16* __restrict__ w2b,
    int* __restrict__ tope, float2* __restrict__ gate2,
    int* __restrict__ counts) {
  int blk = blockIdx.x;
  if (blk < T_TOK / 4) {
    int wave = threadIdx.x >> 6;
    int lane = threadIdx.x & 63;
    int t = blk * 4 + wave;
    const float4* x4 = (const float4*)(x + (size_t)t * H_DIM);
    const float4* rw4 = (const float4*)rw;
    u16* xbrow = xb + (size_t)t * H_DIM;

    double acc[NE];
#pragma unroll
    for (int e = 0; e < NE; e++) acc[e] = 0.0;
#pragma unroll
    for (int i = 0; i < 4; i++) {
      int c = lane + 64 * i;
      float4 xv = x4[c];
      ushort4 bv = make_ushort4(f32_to_bf16(xv.x), f32_to_bf16(xv.y),
                                f32_to_bf16(xv.z), f32_to_bf16(xv.w));
      *(ushort4*)(xbrow + c * 4) = bv;
#pragma unroll
      for (int e = 0; e < NE; e++) {
        float4 wv = rw4[e * 256 + c];
        acc[e] += (double)xv.x * wv.x + (double)xv.y * wv.y +
                  (double)xv.z * wv.z + (double)xv.w * wv.w;
      }
    }
#pragma unroll
    for (int off = 32; off >= 1; off >>= 1)
#pragma unroll
      for (int e = 0; e < NE; e++) acc[e] += __shfl_xor(acc[e], off, 64);

    if (lane == 0) {
      int e0 = 0; double v0 = acc[0];
#pragma unroll
      for (int e = 1; e < NE; e++) if (acc[e] > v0) { v0 = acc[e]; e0 = e; }
      int e1 = -1; double v1 = -1e300;
#pragma unroll
      for (int e = 0; e < NE; e++) if (e != e0 && acc[e] > v1) { v1 = acc[e]; e1 = e; }
      double ex = exp(v1 - v0);
      tope[t] = e0 | (e1 << 8);
      gate2[t] = make_float2((float)(1.0 / (1.0 + ex)), (float)(ex / (1.0 + ex)));
    }
  } else {
    int cb = blk - T_TOK / 4;
    if (cb == 0 && threadIdx.x < NE) counts[threadIdx.x] = 0;
    const float* src; u16* dst;
    if (cb < 3072) { src = w1; dst = w1b; }
    else           { src = w2; dst = w2b; cb -= 3072; }
    const int n4 = NE * H2 * H_DIM / 4;
    const int stride = 3072 * 256;
    const float4* s4 = (const float4*)src;
    for (int i = cb * 256 + threadIdx.x; i < n4; i += stride) {
      float4 v = s4[i];
      *(ushort4*)(dst + (size_t)i * 4) = make_ushort4(
          f32_to_bf16(v.x), f32_to_bf16(v.y), f32_to_bf16(v.z), f32_to_bf16(v.w));
    }
  }
}

// ---------------- Build expert lists: counting sort over 8 bins.
__global__ __launch_bounds__(256) void build_kernel(
    const int* __restrict__ tope, int* __restrict__ counts,
    int* __restrict__ tok_list, int2* __restrict__ pos2) {
  __shared__ int cts[4][NE];
  __shared__ int gbase[NE];
  int tid = threadIdx.x, lane = tid & 63, w = tid >> 6;
  int t = blockIdx.x * 256 + tid;
  int pk = tope[t];
  int e0 = pk & 0xff, e1 = (pk >> 8) & 0xff;
  unsigned long long lt = ((unsigned long long)1 << lane) - 1;

  int r0 = 0, r1 = 0;
#pragma unroll
  for (int e = 0; e < NE; e++) {
    unsigned long long b0 = __ballot(e0 == e);
    unsigned long long b1 = __ballot(e1 == e);
    int n0 = __popcll(b0), n1 = __popcll(b1);
    if (e0 == e) r0 = __popcll(b0 & lt);
    if (e1 == e) r1 = n0 + __popcll(b1 & lt);
    if (lane == 0) cts[w][e] = n0 + n1;
  }
  __syncthreads();
  if (tid < NE) {
    int bt = cts[0][tid] + cts[1][tid] + cts[2][tid] + cts[3][tid];
    gbase[tid] = atomicAdd(&counts[tid], bt);
  }
  __syncthreads();
  int off0 = gbase[e0] + r0;
  int off1 = gbase[e1] + r1;
#pragma unroll
  for (int wp = 0; wp < 4; wp++) {
    if (wp < w) { off0 += cts[wp][e0]; off1 += cts[wp][e1]; }
  }
  tok_list[e0 * T_TOK + off0] = t;
  tok_list[e1 * T_TOK + off1] = t;
  pos2[t] = make_int2(off0, off1);
}

// ---------------- Grouped GEMM, 8-wave 256x256 tile, BK=32, ring-4 LDS
// pipeline (T3+T4+T5 from the 8-phase family, re-derived for a provable
// schedule):
//   * 4 LDS buffers per tensor (16 KB each); iter k reads buf[k&3] and
//     stages tile k+3 into buf[(k+3)&3] == buf[(k-1)&3], whose readers all
//     passed the end-of-iter-(k-1) barrier  -> no WAR race.
//   * end of iter k: s_waitcnt vmcnt(8) retires exactly tile k+1's 4 loads
//     (2 tiles = 8 loads stay IN FLIGHT across the barrier; never drains
//     to 0 in the main loop -- the m218 lever). Tail peels 8->4->0.
//   * raw s_barrier + sched_barrier(0) (NOT __syncthreads: that emits the
//     vmcnt(0) drain this whole design removes).
//   * s_setprio(1) around the 32-MFMA cluster (role-split schedule -> pays).
//   * XOR swizzle for 64B rows: slot = quad ^ ((row>>1)&3); 16 lanes cover
//     all 8 LDS 16B-granules 2x (2-way = free). Staged via pre-swizzled
//     GLOBAL source chunk, LDS dest linear (rule 21).
// Per-wave output 128x64 (2M x 4N waves): 12 ds_read_b128 / 32 MFMA.
template <int NK, int NT, int OUTN, bool GATHER, bool GELU>
__global__ __launch_bounds__(512, 2) void moe_gemm(
    const u16* __restrict__ A, const u16* __restrict__ W,
    u16* __restrict__ O, const int* __restrict__ tok_list,
    const int* __restrict__ counts) {
  const int MTMAX = T_TOK / 256;  // 32
  int e = blockIdx.x / (MTMAX * NT);
  int rem = blockIdx.x % (MTMAX * NT);
  int mt = rem / NT, nt = rem % NT;
  int cnt = counts[e];
  int m0 = mt * 256;
  if (m0 >= cnt) return;
  int base = prefix_base(counts, e);
  const int K = NK * 32;

  __shared__ u16 lA[4][8192];   // 4 x 256x32 bf16 = 64 KB
  __shared__ u16 lB[4][8192];   // 64 KB

  int tid = threadIdx.x;
  int lane = tid & 63, wave = tid >> 6;
  int wr = wave >> 2, wc = wave & 3;       // 2M x 4N wave grid
  int quad = lane >> 4, l16 = lane & 15;

  // ---- staging addresses (fixed rows; only K advances per tile)
  int cg = (tid & 3) ^ ((tid >> 3) & 3);   // pre-swizzled source chunk
  const u16* We = W + (size_t)e * OUTN * K;
  const u16* asrc[2]; const u16* bsrc[2];
#pragma unroll
  for (int r = 0; r < 2; ++r) {
    int row = (tid >> 2) + 128 * r;        // row within 256-row tile
    int ar = m0 + row; if (ar > cnt - 1) ar = cnt - 1;
    if (GATHER) asrc[r] = A + (size_t)tok_list[e * T_TOK + ar] * K + cg * 8;
    else        asrc[r] = A + (size_t)(base + ar) * K + cg * 8;
    bsrc[r] = We + (size_t)(nt * 256 + row) * K + cg * 8;
  }

  auto stage = [&](int kt) {
    int b = kt & 3;
#pragma unroll
    for (int r = 0; r < 2; ++r) {
      g2l16(asrc[r] + kt * 32, &lA[b][r * 4096 + tid * 8]);
      g2l16(bsrc[r] + kt * 32, &lB[b][r * 4096 + tid * 8]);
    }
  };

  f32x4 acc[8][4];
#pragma unroll
  for (int i = 0; i < 8; i++)
#pragma unroll
    for (int j = 0; j < 4; j++)
#pragma unroll
      for (int r = 0; r < 4; r++) acc[i][j][r] = 0.f;

  // prologue: tiles 0..2 in flight; wait for tile 0 only (vmcnt 12->8)
  stage(0); stage(1); stage(2);
  asm volatile("s_waitcnt vmcnt(8)" ::: "memory");
  __builtin_amdgcn_s_barrier();
  __builtin_amdgcn_sched_barrier(0);

  int aoff = (wr * 128 + l16) * 32 + (quad ^ ((l16 >> 1) & 3)) * 8;
  int boff = (wc * 64 + l16) * 32 + (quad ^ ((l16 >> 1) & 3)) * 8;

#pragma unroll 1
  for (int k = 0; k < NK; ++k) {
    const u16* Ab = &lA[k & 3][0] + aoff;
    const u16* Bb = &lB[k & 3][0] + boff;
    bf16x8 af[8], bfr[4];
#pragma unroll
    for (int mi = 0; mi < 8; ++mi)
      af[mi] = *(const bf16x8*)(Ab + mi * 512);     // +1KB imm offsets
#pragma unroll
    for (int ni = 0; ni < 4; ++ni)
      bfr[ni] = *(const bf16x8*)(Bb + ni * 512);

    if (k + 3 < NK) stage(k + 3);

    __builtin_amdgcn_s_setprio(1);
#pragma unroll
    for (int mi = 0; mi < 8; ++mi)
#pragma unroll
      for (int ni = 0; ni < 4; ++ni)
        acc[mi][ni] = __builtin_amdgcn_mfma_f32_16x16x32_bf16(
            af[mi], bfr[ni], acc[mi][ni], 0, 0, 0);
    __builtin_amdgcn_s_setprio(0);

    if (k + 3 < NK)      asm volatile("s_waitcnt vmcnt(8)" ::: "memory");
    else if (k + 2 < NK) asm volatile("s_waitcnt vmcnt(4)" ::: "memory");
    else if (k + 1 < NK) asm volatile("s_waitcnt vmcnt(0)" ::: "memory");
    if (k + 1 < NK) {
      __builtin_amdgcn_s_barrier();
      __builtin_amdgcn_sched_barrier(0);
    }
  }

  // epilogue: C/D layout col=lane&15, row=quad*4+reg
#pragma unroll
  for (int mi = 0; mi < 8; ++mi) {
    int rb = wr * 128 + mi * 16 + quad * 4;
#pragma unroll
    for (int r = 0; r < 4; ++r) {
      int grow = m0 + rb + r;
      if (grow < cnt) {
        size_t o = (size_t)(base + grow) * OUTN + nt * 256 + wc * 64 + l16;
#pragma unroll
        for (int ni = 0; ni < 4; ++ni) {
          float v = acc[mi][ni][r];
          if (GELU) v = fast_gelu(v);
          O[o + ni * 16] = f32_to_bf16(v);
        }
      }
    }
  }
}

// ---------------- Combine: out[t] = g0*y[slot0(t)] + g1*y[slot1(t)]
__global__ __launch_bounds__(256) void combine_kernel(
    const u16* __restrict__ y, const int* __restrict__ tope,
    const float2* __restrict__ gate2, const int2* __restrict__ pos2,
    const int* __restrict__ counts, float* __restrict__ out) {
  int t = blockIdx.x;
  int pk = tope[t];
  int e0 = pk & 0xff, e1 = (pk >> 8) & 0xff;
  float2 g = gate2[t];
  int2 p = pos2[t];
  int hb0 = prefix_base(counts, e0);
  int hb1 = prefix_base(counts, e1);
  size_t s0 = (size_t)(hb0 + p.x) * H_DIM + threadIdx.x * 4;
  size_t s1 = (size_t)(hb1 + p.y) * H_DIM + threadIdx.x * 4;
  ushort4 a = *(const ushort4*)(y + s0);
  ushort4 b = *(const ushort4*)(y + s1);
  float4 o;
  o.x = g.x * bf2f(a.x) + g.y * bf2f(b.x);
  o.y = g.x * bf2f(a.y) + g.y * bf2f(b.y);
  o.z = g.x * bf2f(a.z) + g.y * bf2f(b.z);
  o.w = g.x * bf2f(a.w) + g.y * bf2f(b.w);
  *(float4*)(out + (size_t)t * H_DIM + threadIdx.x * 4) = o;
}

extern "C" void kernel_launch(void* const* d_in, const int* in_sizes, int n_in,
                              void* d_out, int out_size, void* d_ws, size_t ws_size,
                              hipStream_t stream) {
  const float* x  = (const float*)d_in[0];
  const float* rw = (const float*)d_in[1];
  const float* w1 = (const float*)d_in[2];
  const float* w2 = (const float*)d_in[3];
  float* out = (float*)d_out;

  // ws layout (bytes), total ~151.5 MB. y aliases w1b (dead after g1).
  char* ws = (char*)d_ws;
  u16* xb       = (u16*)(ws);                        // 16,777,216
  u16* w1b      = (u16*)(ws + 16777216);             // 33,554,432
  u16* y        = (u16*)(ws + 16777216);             // alias of w1b
  u16* w2b      = (u16*)(ws + 50331648);             // 33,554,432
  u16* h        = (u16*)(ws + 83886080);             // 67,108,864
  int* tok_list = (int*)(ws + 150994944);            // 262,144
  int* tope     = (int*)(ws + 151257088);            // 32,768
  float2* gate2 = (float2*)(ws + 151289856);         // 65,536
  int2* pos2    = (int2*)(ws + 151355392);           // 65,536
  int* counts   = (int*)(ws + 151420928);            // 32

  prep_kernel<<<T_TOK / 4 + 6144, 256, 0, stream>>>(x, rw, w1, w2, xb, w1b, w2b,
                                                    tope, gate2, counts);
  build_kernel<<<T_TOK / 256, 256, 0, stream>>>(tope, counts, tok_list, pos2);
  // g1: [cnt_e,1024] @ w1[e]^T -> gelu -> h [.,2048]; gather rows via tok_list
  moe_gemm<32, 8, H2, true, true>
      <<<NE * 32 * 8, 512, 0, stream>>>(xb, w1b, h, tok_list, counts);
  // g2: h [cnt_e,2048] @ w2[e]^T -> y [.,1024]
  moe_gemm<64, 4, H_DIM, false, false>
      <<<NE * 32 * 4, 512, 0, stream>>>(h, w2b, y, tok_list, counts);
  combine_kernel<<<T_TOK, 256, 0, stream>>>(y, tope, gate2, pos2, counts, out);
}